// Round 1
// 1091.741 us; speedup vs baseline: 1.0020x; 1.0020x over previous
//
#include <hip/hip_runtime.h>

#define GG 4
#define TT 2048
#define EE 8
#define DD 1024
#define CC 2048

static constexpr long long GTEC = (long long)GG * TT * EE * CC; // 134217728
// Exact output footprint in BYTES: dispatch[G,T,E,C] + combine[G,T,E,C] + z_loss scalar.
// NOTE: rocprof showed the previous `out_size * sizeof(float)` memset wrote 4.295 GB
// (4x this), i.e. out_size is already a byte count. Zero exactly what the output needs.
static constexpr size_t OUT_BYTES = (size_t)(2 * GTEC + 1) * sizeof(float); // 1073741828

// ---------------------------------------------------------------------------
// Kernel A: router logits -> softmax probs [G*T, E] in ws, z_loss atomic add.
// One wave per token; W (8x1024 = 32KB) staged in LDS.
// ---------------------------------------------------------------------------
__global__ __launch_bounds__(256) void router_probs_kernel(
    const float* __restrict__ x, const float* __restrict__ W,
    const float* __restrict__ bias, float* __restrict__ probs,
    float* __restrict__ zloss)
{
    __shared__ float sW[EE * DD];   // 32 KB
    __shared__ float zpart[4];
    for (int i = threadIdx.x; i < EE * DD; i += 256) sW[i] = W[i];
    __syncthreads();

    const int wave = threadIdx.x >> 6;
    const int lane = threadIdx.x & 63;
    const int token = blockIdx.x * 4 + wave;   // grid = GG*TT/4, exact
    const float* xr = x + (long long)token * DD;

    float acc[EE];
#pragma unroll
    for (int e = 0; e < EE; ++e) acc[e] = 0.f;

#pragma unroll 4
    for (int k = lane; k < DD; k += 64) {
        float xv = xr[k];
#pragma unroll
        for (int e = 0; e < EE; ++e)
            acc[e] = fmaf(xv, sW[e * DD + k], acc[e]);
    }

    // butterfly reduce across the 64-lane wave
#pragma unroll
    for (int off = 32; off > 0; off >>= 1) {
#pragma unroll
        for (int e = 0; e < EE; ++e)
            acc[e] += __shfl_xor(acc[e], off, 64);
    }

#pragma unroll
    for (int e = 0; e < EE; ++e) acc[e] += bias[e];

    float m = acc[0];
#pragma unroll
    for (int e = 1; e < EE; ++e) m = fmaxf(m, acc[e]);
    float s = 0.f;
#pragma unroll
    for (int e = 0; e < EE; ++e) s += expf(acc[e] - m);
    float lse = m + logf(s);

    if (lane < EE)
        probs[(long long)token * EE + lane] = expf(acc[lane] - lse);

    if (lane == 0) {
        float zs = 0.f;
#pragma unroll
        for (int e = 0; e < EE; ++e) {
            float d = acc[e] - lse;
            zs = fmaf(d, d, zs);
        }
        zpart[wave] = zs;
    }
    __syncthreads();
    if (threadIdx.x == 0) {
        float zb = (zpart[0] + zpart[1]) + (zpart[2] + zpart[3]);
        atomicAdd(zloss, zb * (1.0f / ((float)GG * TT * EE)));
    }
}

// ---------------------------------------------------------------------------
// Kernel B: one block per (g,e). Bitonic-sort 2048 (prob, token) keys
// descending (ties -> lower token index first), then scatter:
//   dispatch[g, t, e, c] = 1.0f ; combine[g, t, e, c] = gate
// ---------------------------------------------------------------------------
__global__ __launch_bounds__(1024) void topk_scatter_kernel(
    const float* __restrict__ probs, float* __restrict__ out)
{
    __shared__ unsigned long long keys[TT];   // 16 KB
    const int g = blockIdx.x >> 3;
    const int e = blockIdx.x & 7;
    const int caps[EE] = {512, 512, 256, 256, 128, 128, 128, 128};
    const int cap = caps[e];

    for (int t = threadIdx.x; t < TT; t += 1024) {
        float p = probs[((long long)g * TT + t) * EE + e];
        unsigned int pb = __float_as_uint(p);   // p > 0: uint order == float order
        keys[t] = ((unsigned long long)pb << 32) |
                  (unsigned long long)(0xFFFFFFFFu - (unsigned)t);
    }
    __syncthreads();

    // bitonic sort, descending
    for (int k = 2; k <= TT; k <<= 1) {
        for (int j = k >> 1; j > 0; j >>= 1) {
            for (int v = threadIdx.x; v < TT; v += 1024) {
                int ixj = v ^ j;
                if (ixj > v) {
                    bool desc = ((v & k) == 0);
                    unsigned long long a = keys[v];
                    unsigned long long b = keys[ixj];
                    bool sw = desc ? (a < b) : (a > b);
                    if (sw) { keys[v] = b; keys[ixj] = a; }
                }
            }
            __syncthreads();
        }
    }

    if (threadIdx.x < cap) {
        unsigned long long kk = keys[threadIdx.x];
        int t = (int)(0xFFFFFFFFu - (unsigned)(kk & 0xFFFFFFFFull));
        float gate = __uint_as_float((unsigned)(kk >> 32));
        long long base = (((long long)g * TT + t) * EE + e) * CC + threadIdx.x;
        out[base] = 1.0f;            // dispatch_mask (read back as float32)
        out[GTEC + base] = gate;     // combine_array
    }
}

extern "C" void kernel_launch(void* const* d_in, const int* in_sizes, int n_in,
                              void* d_out, int out_size, void* d_ws, size_t ws_size,
                              hipStream_t stream) {
    const float* x    = (const float*)d_in[0];
    const float* W    = (const float*)d_in[1];
    const float* bias = (const float*)d_in[2];
    float* out   = (float*)d_out;
    float* probs = (float*)d_ws;                  // G*T*E floats = 256 KB

    // zero exactly the output region (d_out is poisoned each launch).
    // Previous version used out_size*sizeof(float) which rocprof showed to be
    // 4.295 GB written (out_size is a byte count) -> 520 us of wasted HBM writes.
    hipMemsetAsync(d_out, 0, OUT_BYTES, stream);

    router_probs_kernel<<<GG * TT / 4, 256, 0, stream>>>(
        x, W, bias, probs, out + 2 * GTEC);

    topk_scatter_kernel<<<GG * EE, 1024, 0, stream>>>(probs, out);
}